// Round 4
// baseline (650.691 us; speedup 1.0000x reference)
//
#include <hip/hip_runtime.h>
#include <math.h>

#define NN 20000      // nodes
#define NE 320000     // edges
#define NG 64         // graphs
#define IND 128
#define HIDD 256
#define NH 4
#define ED 5
#define NACT 8
#define NEG 0.2f
#define MAXDEG 64

// ---------------- generic tiled fp32 GEMM: C[M,Ncol] = A[M,K] @ B[K,Ncol] ----------------
// BM=BN=64, BK=32, 256 threads, 4x4 per thread.
__global__ __launch_bounds__(256) void gemm64(const float* __restrict__ A,
    const float* __restrict__ B, float* __restrict__ C, int M, int K, int Ncol)
{
    const int BK = 32;
    __shared__ float As[32][68];   // [k][m], padded to 68 to break write conflicts
    __shared__ float Bs[32][64];   // [k][n]
    int bm = blockIdx.x * 64, bn = blockIdx.y * 64;
    int tid = threadIdx.x;
    int tx = tid & 15, ty = tid >> 4;
    float acc[4][4] = {};
    for (int k0 = 0; k0 < K; k0 += BK) {
        for (int idx = tid; idx < 64 * BK; idx += 256) {
            int r = idx >> 5, c = idx & 31;
            int gr = bm + r;
            As[c][r] = (gr < M) ? A[(size_t)gr * K + k0 + c] : 0.f;
        }
        for (int idx = tid; idx < BK * 64; idx += 256) {
            int r = idx >> 6, c = idx & 63;
            Bs[r][c] = B[(size_t)(k0 + r) * Ncol + bn + c];
        }
        __syncthreads();
        #pragma unroll
        for (int k = 0; k < BK; ++k) {
            float4 a4 = *(const float4*)&As[k][ty * 4];
            float4 b4 = *(const float4*)&Bs[k][tx * 4];
            float a[4] = {a4.x, a4.y, a4.z, a4.w};
            float b[4] = {b4.x, b4.y, b4.z, b4.w};
            #pragma unroll
            for (int i = 0; i < 4; ++i)
                #pragma unroll
                for (int j = 0; j < 4; ++j)
                    acc[i][j] = fmaf(a[i], b[j], acc[i][j]);
        }
        __syncthreads();
    }
    #pragma unroll
    for (int i = 0; i < 4; ++i) {
        int r = bm + ty * 4 + i;
        if (r < M) {
            float4 v = {acc[i][0], acc[i][1], acc[i][2], acc[i][3]};
            *(float4*)&C[(size_t)r * Ncol + bn + tx * 4] = v;
        }
    }
}

// ---------------- inverse adjacency: per-dst fixed slots ----------------
__global__ __launch_bounds__(256) void build_slots(const int* __restrict__ dst,
    int* __restrict__ deg, int* __restrict__ slots)
{
    int e = blockIdx.x * 256 + threadIdx.x;
    if (e >= NE) return;
    int d = dst[e];
    int pos = atomicAdd(&deg[d], 1);
    if (pos < MAXDEG) slots[d * MAXDEG + pos] = e;
}

// ---------------- layer-1 edge logits (4 heads), wave per edge ----------------
__global__ __launch_bounds__(256) void edge_logits1(
    const int* __restrict__ src, const int* __restrict__ dst,
    const float* __restrict__ eattr,
    const float* __restrict__ xl, const float* __restrict__ xr,
    const float* __restrict__ We, const float* __restrict__ attw,
    float* __restrict__ expl)
{
    __shared__ float sWe[ED * HIDD];
    __shared__ float sAtt[HIDD];
    for (int i = threadIdx.x; i < ED * HIDD; i += 256) sWe[i] = We[i];
    for (int i = threadIdx.x; i < HIDD; i += 256) sAtt[i] = attw[i];
    __syncthreads();
    int wave = threadIdx.x >> 6, lane = threadIdx.x & 63;
    #pragma unroll
    for (int it = 0; it < 4; ++it) {
        int e = blockIdx.x * 16 + it * 4 + wave;
        int s = src[e], d = dst[e];
        float ea[ED];
        #pragma unroll
        for (int k = 0; k < ED; ++k) ea[k] = eattr[(size_t)e * ED + k];
        float4 xl4 = *(const float4*)(xl + (size_t)s * HIDD + lane * 4);
        float4 xr4 = *(const float4*)(xr + (size_t)d * HIDD + lane * 4);
        float xla[4] = {xl4.x, xl4.y, xl4.z, xl4.w};
        float xra[4] = {xr4.x, xr4.y, xr4.z, xr4.w};
        float partial = 0.f;
        #pragma unroll
        for (int j = 0; j < 4; ++j) {
            int c = lane * 4 + j;
            float ev = 0.f;
            #pragma unroll
            for (int k = 0; k < ED; ++k) ev = fmaf(ea[k], sWe[k * HIDD + c], ev);
            float m = xla[j] + xra[j] + ev;
            m = m > 0.f ? m : NEG * m;
            partial = fmaf(m, sAtt[c], partial);
        }
        #pragma unroll
        for (int off = 1; off < 16; off <<= 1)
            partial += __shfl_xor(partial, off, 64);
        if ((lane & 15) == 0)
            expl[e * NH + (lane >> 4)] = expf(partial);
    }
}

// ---------------- layer-2 edge logits (1 head), wave per edge ----------------
__global__ __launch_bounds__(256) void edge_logits2(
    const int* __restrict__ src, const int* __restrict__ dst,
    const float* __restrict__ eattr,
    const float* __restrict__ xl, const float* __restrict__ xr,
    const float* __restrict__ We, const float* __restrict__ attw,
    float* __restrict__ expl)
{
    __shared__ float sWe[ED * HIDD];
    __shared__ float sAtt[HIDD];
    for (int i = threadIdx.x; i < ED * HIDD; i += 256) sWe[i] = We[i];
    for (int i = threadIdx.x; i < HIDD; i += 256) sAtt[i] = attw[i];
    __syncthreads();
    int wave = threadIdx.x >> 6, lane = threadIdx.x & 63;
    #pragma unroll
    for (int it = 0; it < 4; ++it) {
        int e = blockIdx.x * 16 + it * 4 + wave;
        int s = src[e], d = dst[e];
        float ea[ED];
        #pragma unroll
        for (int k = 0; k < ED; ++k) ea[k] = eattr[(size_t)e * ED + k];
        float4 xl4 = *(const float4*)(xl + (size_t)s * HIDD + lane * 4);
        float4 xr4 = *(const float4*)(xr + (size_t)d * HIDD + lane * 4);
        float xla[4] = {xl4.x, xl4.y, xl4.z, xl4.w};
        float xra[4] = {xr4.x, xr4.y, xr4.z, xr4.w};
        float partial = 0.f;
        #pragma unroll
        for (int j = 0; j < 4; ++j) {
            int c = lane * 4 + j;
            float ev = 0.f;
            #pragma unroll
            for (int k = 0; k < ED; ++k) ev = fmaf(ea[k], sWe[k * HIDD + c], ev);
            float m = xla[j] + xra[j] + ev;
            m = m > 0.f ? m : NEG * m;
            partial = fmaf(m, sAtt[c], partial);
        }
        #pragma unroll
        for (int off = 1; off < 32; off <<= 1)
            partial += __shfl_xor(partial, off, 64);
        if (lane == 0)
            expl[e] = expf(partial);
    }
}

// ---------------- per-node aggregation, layer 1 (4 heads), wave per node ----------------
__global__ __launch_bounds__(256) void node_agg1(
    const int* __restrict__ deg, const int* __restrict__ slots,
    const int* __restrict__ src,
    const float* __restrict__ xl, const float* __restrict__ expl,
    float* __restrict__ out)
{
    int wave = threadIdx.x >> 6, lane = threadIdx.x & 63;
    int n = blockIdx.x * 4 + wave;
    int dg = min(deg[n], MAXDEG);
    // denominators per head (sum of exp over in-edges)
    float p[NH] = {0.f, 0.f, 0.f, 0.f};
    if (lane < dg) {
        int e = slots[n * MAXDEG + lane];
        float4 ex = *(const float4*)(expl + (size_t)e * NH);
        p[0] = ex.x; p[1] = ex.y; p[2] = ex.z; p[3] = ex.w;
    }
    #pragma unroll
    for (int off = 32; off; off >>= 1) {
        #pragma unroll
        for (int h = 0; h < NH; ++h) p[h] += __shfl_xor(p[h], off, 64);
    }
    int h = lane >> 4;
    float inv = 1.f / (p[h] + 1e-16f);
    float4 acc = {0.f, 0.f, 0.f, 0.f};
    for (int i = 0; i < dg; ++i) {
        int e = slots[n * MAXDEG + i];
        int s = src[e];
        float a = expl[(size_t)e * NH + h] * inv;
        float4 x = *(const float4*)(xl + (size_t)s * HIDD + lane * 4);
        acc.x = fmaf(a, x.x, acc.x);
        acc.y = fmaf(a, x.y, acc.y);
        acc.z = fmaf(a, x.z, acc.z);
        acc.w = fmaf(a, x.w, acc.w);
    }
    *(float4*)(out + (size_t)n * HIDD + lane * 4) = acc;
}

// ---------------- per-node aggregation, layer 2 (1 head), wave per node ----------------
__global__ __launch_bounds__(256) void node_agg2(
    const int* __restrict__ deg, const int* __restrict__ slots,
    const int* __restrict__ src,
    const float* __restrict__ xl, const float* __restrict__ expl,
    float* __restrict__ out)
{
    int wave = threadIdx.x >> 6, lane = threadIdx.x & 63;
    int n = blockIdx.x * 4 + wave;
    int dg = min(deg[n], MAXDEG);
    float p = 0.f;
    if (lane < dg) p = expl[slots[n * MAXDEG + lane]];
    #pragma unroll
    for (int off = 32; off; off >>= 1) p += __shfl_xor(p, off, 64);
    float inv = 1.f / (p + 1e-16f);
    float4 acc = {0.f, 0.f, 0.f, 0.f};
    for (int i = 0; i < dg; ++i) {
        int e = slots[n * MAXDEG + i];
        int s = src[e];
        float a = expl[e] * inv;
        float4 x = *(const float4*)(xl + (size_t)s * HIDD + lane * 4);
        acc.x = fmaf(a, x.x, acc.x);
        acc.y = fmaf(a, x.y, acc.y);
        acc.z = fmaf(a, x.z, acc.z);
        acc.w = fmaf(a, x.w, acc.w);
    }
    *(float4*)(out + (size_t)n * HIDD + lane * 4) = acc;
}

// ---------------- bias + relu in place ----------------
__global__ __launch_bounds__(256) void bias_relu(float* __restrict__ x,
    const float* __restrict__ b)
{
    int i = blockIdx.x * 256 + threadIdx.x;
    float v = x[i] + b[i & (HIDD - 1)];
    x[i] = v > 0.f ? v : 0.f;
}

// ---------------- global mean pool (batch is sorted) ----------------
#define POOL_CHUNK 128
__global__ __launch_bounds__(256) void pool_kernel(
    const float* __restrict__ h, const int* __restrict__ batch,
    float* __restrict__ pool, float* __restrict__ cnt)
{
    int c = threadIdx.x;
    int start = blockIdx.x * POOL_CHUNK;
    int end = min(start + POOL_CHUNK, NN);
    if (start >= NN) return;
    float acc = 0.f;
    int cur = batch[start];
    int localCount = 0;
    for (int n = start; n < end; ++n) {
        int g = batch[n];
        if (g != cur) {
            atomicAdd(&pool[cur * HIDD + c], acc);
            if (c == 0) atomicAdd(&cnt[cur], (float)localCount);
            acc = 0.f; localCount = 0; cur = g;
        }
        acc += h[(size_t)n * HIDD + c];
        ++localCount;
    }
    atomicAdd(&pool[cur * HIDD + c], acc);
    if (c == 0) atomicAdd(&cnt[cur], (float)localCount);
}

// ---------------- heads: logits [G,8] and value [G], out [G,9] ----------------
__global__ __launch_bounds__(256) void head_kernel(
    const float* __restrict__ pool, const float* __restrict__ cnt,
    const float* __restrict__ Wp, const float* __restrict__ bp,
    const float* __restrict__ Wv, const float* __restrict__ bv,
    float* __restrict__ out)
{
    int g = blockIdx.x;
    int c = threadIdx.x;
    float gv = pool[g * HIDD + c] / fmaxf(cnt[g], 1.0f);
    __shared__ float red[256];
    for (int j = 0; j < NACT + 1; ++j) {
        float w = (j < NACT) ? Wp[c * NACT + j] : Wv[c];
        red[c] = gv * w;
        __syncthreads();
        for (int sl = 128; sl > 0; sl >>= 1) {
            if (c < sl) red[c] += red[c + sl];
            __syncthreads();
        }
        if (c == 0) out[g * (NACT + 1) + j] = red[0] + ((j < NACT) ? bp[j] : bv[0]);
        __syncthreads();
    }
}

extern "C" void kernel_launch(void* const* d_in, const int* in_sizes, int n_in,
                              void* d_out, int out_size, void* d_ws, size_t ws_size,
                              hipStream_t stream)
{
    const float* x    = (const float*)d_in[0];
    const int*   ei   = (const int*)d_in[1];
    const int*   batch= (const int*)d_in[2];
    const float* ea   = (const float*)d_in[3];
    const float* W1l  = (const float*)d_in[4];
    const float* W1r  = (const float*)d_in[5];
    const float* W1e  = (const float*)d_in[6];
    const float* att1 = (const float*)d_in[7];
    const float* b1   = (const float*)d_in[8];
    const float* W2l  = (const float*)d_in[9];
    const float* W2r  = (const float*)d_in[10];
    const float* W2e  = (const float*)d_in[11];
    const float* att2 = (const float*)d_in[12];
    const float* b2   = (const float*)d_in[13];
    const float* Wp   = (const float*)d_in[14];
    const float* bp   = (const float*)d_in[15];
    const float* Wv   = (const float*)d_in[16];
    const float* bv   = (const float*)d_in[17];
    const int* src = ei;
    const int* dst = ei + NE;
    float* out = (float*)d_out;

    // workspace layout (floats)
    float* ws = (float*)d_ws;
    size_t off = 0;
    float* A     = ws + off; off += (size_t)NN * HIDD;   // xl1 then xl2
    float* B     = ws + off; off += (size_t)NN * HIDD;   // xr1 then xr2
    float* C     = ws + off; off += (size_t)NN * HIDD;   // out1 / h1
    float* D     = ws + off; off += (size_t)NN * HIDD;   // out2 / h2
    float* expl1 = ws + off; off += (size_t)NE * NH;
    float* expl2 = ws + off; off += (size_t)NE;
    float* pool  = ws + off; off += (size_t)NG * HIDD;
    float* cnt   = ws + off; off += NG;
    int*   deg   = (int*)(ws + off); off += NN;
    int*   slots = (int*)(ws + off); off += (size_t)NN * MAXDEG;

    // zero: pool, cnt, deg (contiguous region)
    hipMemsetAsync(pool, 0, (size_t)(NG * HIDD + NG + NN) * sizeof(float), stream);

    // inverse adjacency
    build_slots<<<(NE + 255) / 256, 256, 0, stream>>>(dst, deg, slots);

    // ---- layer 1 ----
    dim3 ggrid((NN + 63) / 64, HIDD / 64);
    gemm64<<<ggrid, 256, 0, stream>>>(x, W1l, A, NN, IND, HIDD);
    gemm64<<<ggrid, 256, 0, stream>>>(x, W1r, B, NN, IND, HIDD);
    edge_logits1<<<NE / 16, 256, 0, stream>>>(src, dst, ea, A, B, W1e, att1, expl1);
    node_agg1<<<NN / 4, 256, 0, stream>>>(deg, slots, src, A, expl1, C);
    bias_relu<<<(NN * HIDD) / 256, 256, 0, stream>>>(C, b1);

    // ---- layer 2 ----
    gemm64<<<ggrid, 256, 0, stream>>>(C, W2l, A, NN, HIDD, HIDD);
    gemm64<<<ggrid, 256, 0, stream>>>(C, W2r, B, NN, HIDD, HIDD);
    edge_logits2<<<NE / 16, 256, 0, stream>>>(src, dst, ea, A, B, W2e, att2, expl2);
    node_agg2<<<NN / 4, 256, 0, stream>>>(deg, slots, src, A, expl2, D);
    bias_relu<<<(NN * HIDD) / 256, 256, 0, stream>>>(D, b2);

    // ---- pool + heads ----
    pool_kernel<<<(NN + POOL_CHUNK - 1) / POOL_CHUNK, 256, 0, stream>>>(D, batch, pool, cnt);
    head_kernel<<<NG, 256, 0, stream>>>(pool, cnt, Wp, bp, Wv, bv, out);
}

// Round 5
// 484.963 us; speedup vs baseline: 1.3417x; 1.3417x over previous
//
#include <hip/hip_runtime.h>
#include <math.h>

#define NN 20000      // nodes
#define NE 320000     // edges
#define NG 64         // graphs
#define IND 128
#define HIDD 256
#define NH 4
#define ED 5
#define NACT 8
#define NEG 0.2f
#define MAXDEG 64

// ---------------- generic tiled fp32 GEMM: C[M,Ncol] = A[M,K] @ B[K,Ncol] ----------------
__global__ __launch_bounds__(256) void gemm64(const float* __restrict__ A,
    const float* __restrict__ B, float* __restrict__ C, int M, int K, int Ncol)
{
    const int BK = 32;
    __shared__ float As[32][68];
    __shared__ float Bs[32][64];
    int bm = blockIdx.x * 64, bn = blockIdx.y * 64;
    int tid = threadIdx.x;
    int tx = tid & 15, ty = tid >> 4;
    float acc[4][4] = {};
    for (int k0 = 0; k0 < K; k0 += BK) {
        for (int idx = tid; idx < 64 * BK; idx += 256) {
            int r = idx >> 5, c = idx & 31;
            int gr = bm + r;
            As[c][r] = (gr < M) ? A[(size_t)gr * K + k0 + c] : 0.f;
        }
        for (int idx = tid; idx < BK * 64; idx += 256) {
            int r = idx >> 6, c = idx & 63;
            Bs[r][c] = B[(size_t)(k0 + r) * Ncol + bn + c];
        }
        __syncthreads();
        #pragma unroll
        for (int k = 0; k < BK; ++k) {
            float4 a4 = *(const float4*)&As[k][ty * 4];
            float4 b4 = *(const float4*)&Bs[k][tx * 4];
            float a[4] = {a4.x, a4.y, a4.z, a4.w};
            float b[4] = {b4.x, b4.y, b4.z, b4.w};
            #pragma unroll
            for (int i = 0; i < 4; ++i)
                #pragma unroll
                for (int j = 0; j < 4; ++j)
                    acc[i][j] = fmaf(a[i], b[j], acc[i][j]);
        }
        __syncthreads();
    }
    #pragma unroll
    for (int i = 0; i < 4; ++i) {
        int r = bm + ty * 4 + i;
        if (r < M) {
            float4 v = {acc[i][0], acc[i][1], acc[i][2], acc[i][3]};
            *(float4*)&C[(size_t)r * Ncol + bn + tx * 4] = v;
        }
    }
}

// ---------------- inverse adjacency: per-dst fixed slots ----------------
__global__ __launch_bounds__(256) void build_slots(const int* __restrict__ dst,
    int* __restrict__ deg, int* __restrict__ slots)
{
    int e = blockIdx.x * 256 + threadIdx.x;
    if (e >= NE) return;
    int d = dst[e];
    int pos = atomicAdd(&deg[d], 1);
    if (pos < MAXDEG) slots[d * MAXDEG + pos] = e;
}

// ---------------- FUSED layer: logits + softmax + aggregation + bias + relu ----------------
// out[n] = relu( (sum_e exp(logit_e) * xl[src_e]) / (sum_e exp(logit_e)) + bias )
// logit_e(head) = att_h . leaky_relu(xl[src_e] + xr[n] + eattr[e]@We), reduced over head's 64 ch.
// Wave per node; lane owns 4 channels (c0 = lane*4); HEADS=4 -> 16-lane groups, HEADS=1 -> 64.
template <int HEADS_T>
__global__ __launch_bounds__(256) void fused_agg(
    const int* __restrict__ deg, const int* __restrict__ slots,
    const int* __restrict__ src, const float* __restrict__ eattr,
    const float* __restrict__ xl, const float* __restrict__ xr,
    const float* __restrict__ We, const float* __restrict__ attw,
    const float* __restrict__ bias, float* __restrict__ out)
{
    __shared__ float sWe[ED * HIDD];
    __shared__ float sAtt[HIDD];
    for (int i = threadIdx.x; i < ED * HIDD; i += 256) sWe[i] = We[i];
    for (int i = threadIdx.x; i < HIDD; i += 256) sAtt[i] = attw[i];
    __syncthreads();

    int wave = threadIdx.x >> 6, lane = threadIdx.x & 63;
    int n = blockIdx.x * 4 + wave;
    int dg = min(deg[n], MAXDEG);
    int c0 = lane * 4;

    // per-lane constants in registers
    float attr_[4], wer[ED][4];
    #pragma unroll
    for (int j = 0; j < 4; ++j) attr_[j] = sAtt[c0 + j];
    #pragma unroll
    for (int k = 0; k < ED; ++k)
        #pragma unroll
        for (int j = 0; j < 4; ++j) wer[k][j] = sWe[k * HIDD + c0 + j];

    float4 xr4 = *(const float4*)(xr + (size_t)n * HIDD + c0);
    float xra[4] = {xr4.x, xr4.y, xr4.z, xr4.w};

    float denom = 0.f;
    float acc[4] = {0.f, 0.f, 0.f, 0.f};

    const int* slotrow = slots + (size_t)n * MAXDEG;
    for (int i = 0; i < dg; ++i) {
        int e = slotrow[i];
        int s = src[e];
        float4 xl4 = *(const float4*)(xl + (size_t)s * HIDD + c0);
        float xla[4] = {xl4.x, xl4.y, xl4.z, xl4.w};
        float ea[ED];
        #pragma unroll
        for (int k = 0; k < ED; ++k) ea[k] = eattr[(size_t)e * ED + k];
        float partial = 0.f;
        #pragma unroll
        for (int j = 0; j < 4; ++j) {
            float ev = 0.f;
            #pragma unroll
            for (int k = 0; k < ED; ++k) ev = fmaf(ea[k], wer[k][j], ev);
            float m = xla[j] + xra[j] + ev;
            m = m > 0.f ? m : NEG * m;
            partial = fmaf(m, attr_[j], partial);
        }
        // butterfly reduce across the head's lane group (16 lanes for 4 heads, 64 for 1)
        if (HEADS_T == 4) {
            #pragma unroll
            for (int off = 1; off < 16; off <<= 1)
                partial += __shfl_xor(partial, off, 64);
        } else {
            #pragma unroll
            for (int off = 1; off < 64; off <<= 1)
                partial += __shfl_xor(partial, off, 64);
        }
        float ex = expf(partial);
        denom += ex;
        #pragma unroll
        for (int j = 0; j < 4; ++j) acc[j] = fmaf(ex, xla[j], acc[j]);
    }
    float inv = 1.f / (denom + 1e-16f);
    float4 o;
    o.x = fmaxf(acc[0] * inv + bias[c0 + 0], 0.f);
    o.y = fmaxf(acc[1] * inv + bias[c0 + 1], 0.f);
    o.z = fmaxf(acc[2] * inv + bias[c0 + 2], 0.f);
    o.w = fmaxf(acc[3] * inv + bias[c0 + 3], 0.f);
    *(float4*)(out + (size_t)n * HIDD + c0) = o;
}

// ---------------- global mean pool (batch is sorted) ----------------
#define POOL_CHUNK 128
__global__ __launch_bounds__(256) void pool_kernel(
    const float* __restrict__ h, const int* __restrict__ batch,
    float* __restrict__ pool, float* __restrict__ cnt)
{
    int c = threadIdx.x;
    int start = blockIdx.x * POOL_CHUNK;
    int end = min(start + POOL_CHUNK, NN);
    if (start >= NN) return;
    float acc = 0.f;
    int cur = batch[start];
    int localCount = 0;
    for (int n = start; n < end; ++n) {
        int g = batch[n];
        if (g != cur) {
            atomicAdd(&pool[cur * HIDD + c], acc);
            if (c == 0) atomicAdd(&cnt[cur], (float)localCount);
            acc = 0.f; localCount = 0; cur = g;
        }
        acc += h[(size_t)n * HIDD + c];
        ++localCount;
    }
    atomicAdd(&pool[cur * HIDD + c], acc);
    if (c == 0) atomicAdd(&cnt[cur], (float)localCount);
}

// ---------------- heads: logits [G,8] and value [G], out [G,9] ----------------
__global__ __launch_bounds__(256) void head_kernel(
    const float* __restrict__ pool, const float* __restrict__ cnt,
    const float* __restrict__ Wp, const float* __restrict__ bp,
    const float* __restrict__ Wv, const float* __restrict__ bv,
    float* __restrict__ out)
{
    int g = blockIdx.x;
    int c = threadIdx.x;
    float gv = pool[g * HIDD + c] / fmaxf(cnt[g], 1.0f);
    __shared__ float red[256];
    for (int j = 0; j < NACT + 1; ++j) {
        float w = (j < NACT) ? Wp[c * NACT + j] : Wv[c];
        red[c] = gv * w;
        __syncthreads();
        for (int sl = 128; sl > 0; sl >>= 1) {
            if (c < sl) red[c] += red[c + sl];
            __syncthreads();
        }
        if (c == 0) out[g * (NACT + 1) + j] = red[0] + ((j < NACT) ? bp[j] : bv[0]);
        __syncthreads();
    }
}

extern "C" void kernel_launch(void* const* d_in, const int* in_sizes, int n_in,
                              void* d_out, int out_size, void* d_ws, size_t ws_size,
                              hipStream_t stream)
{
    const float* x    = (const float*)d_in[0];
    const int*   ei   = (const int*)d_in[1];
    const int*   batch= (const int*)d_in[2];
    const float* ea   = (const float*)d_in[3];
    const float* W1l  = (const float*)d_in[4];
    const float* W1r  = (const float*)d_in[5];
    const float* W1e  = (const float*)d_in[6];
    const float* att1 = (const float*)d_in[7];
    const float* b1   = (const float*)d_in[8];
    const float* W2l  = (const float*)d_in[9];
    const float* W2r  = (const float*)d_in[10];
    const float* W2e  = (const float*)d_in[11];
    const float* att2 = (const float*)d_in[12];
    const float* b2   = (const float*)d_in[13];
    const float* Wp   = (const float*)d_in[14];
    const float* bp   = (const float*)d_in[15];
    const float* Wv   = (const float*)d_in[16];
    const float* bv   = (const float*)d_in[17];
    const int* src = ei;
    const int* dst = ei + NE;
    float* out = (float*)d_out;

    // workspace layout (floats)
    float* ws = (float*)d_ws;
    size_t off = 0;
    float* A     = ws + off; off += (size_t)NN * HIDD;   // xl (layer 1 then layer 2)
    float* B     = ws + off; off += (size_t)NN * HIDD;   // xr (layer 1 then layer 2)
    float* C     = ws + off; off += (size_t)NN * HIDD;   // h1
    float* D     = ws + off; off += (size_t)NN * HIDD;   // h2
    float* pool  = ws + off; off += (size_t)NG * HIDD;
    float* cnt   = ws + off; off += NG;
    int*   deg   = (int*)(ws + off); off += NN;
    int*   slots = (int*)(ws + off); off += (size_t)NN * MAXDEG;

    // zero: pool, cnt, deg (contiguous region)
    hipMemsetAsync(pool, 0, (size_t)(NG * HIDD + NG + NN) * sizeof(float), stream);

    // inverse adjacency
    build_slots<<<(NE + 255) / 256, 256, 0, stream>>>(dst, deg, slots);

    // ---- layer 1 ----
    dim3 ggrid((NN + 63) / 64, HIDD / 64);
    gemm64<<<ggrid, 256, 0, stream>>>(x, W1l, A, NN, IND, HIDD);
    gemm64<<<ggrid, 256, 0, stream>>>(x, W1r, B, NN, IND, HIDD);
    fused_agg<4><<<NN / 4, 256, 0, stream>>>(deg, slots, src, ea, A, B, W1e, att1, b1, C);

    // ---- layer 2 ----
    gemm64<<<ggrid, 256, 0, stream>>>(C, W2l, A, NN, HIDD, HIDD);
    gemm64<<<ggrid, 256, 0, stream>>>(C, W2r, B, NN, HIDD, HIDD);
    fused_agg<1><<<NN / 4, 256, 0, stream>>>(deg, slots, src, ea, A, B, W2e, att2, b2, D);

    // ---- pool + heads ----
    pool_kernel<<<(NN + POOL_CHUNK - 1) / POOL_CHUNK, 256, 0, stream>>>(D, batch, pool, cnt);
    head_kernel<<<NG, 256, 0, stream>>>(pool, cnt, Wp, bp, Wv, bv, out);
}